// Round 1
// baseline (7408.739 us; speedup 1.0000x reference)
//
#include <hip/hip_runtime.h>

#define B_ 8
#define C_ 3
#define H_ 256
#define W_ 256
#define HID_ 32
#define HW_ (H_*W_)            // 65536
#define N_ (B_*H_*W_)          // 524288
#define EH_ (B_*H_*(W_-1))     // 522240 horizontal undirected edges
#define EV_ (B_*(H_-1)*W_)     // 522240 vertical undirected edges
#define U_ (EH_+EV_)           // 1044480
#define K01_ 0xBDCCCCCDu       // fkey(0.1f)

__device__ __forceinline__ unsigned fkey(float f){
  unsigned u = __float_as_uint(f);
  return (u & 0x80000000u) ? ~u : (u | 0x80000000u);
}

__device__ __forceinline__ void edge_uv(int u, int& a, int& b){
  if (u < EH_){
    int w = u % (W_-1); int t = u / (W_-1); int h = t % H_; int bb = t / H_;
    a = (bb*H_+h)*W_+w; b = a+1;
  } else {
    int v = u - EH_;
    int w = v % W_; int t = v / W_; int h = t % (H_-1); int bb = t / (H_-1);
    a = (bb*H_+h)*W_+w; b = a+W_;
  }
}

__global__ __launch_bounds__(256) void k_conv(const float* __restrict__ img,
    const float* __restrict__ cw, const float* __restrict__ cb,
    float* __restrict__ fV){
  __shared__ float w_s[HID_*C_*9];
  __shared__ float b_s[HID_];
  for (int t = threadIdx.x; t < HID_*C_*9; t += blockDim.x) w_s[t] = cw[t];
  if (threadIdx.x < HID_) b_s[threadIdx.x] = cb[threadIdx.x];
  __syncthreads();
  int i = blockIdx.x*blockDim.x + threadIdx.x;
  if (i >= N_) return;
  int b = i / HW_; int rem = i - b*HW_; int h = rem / W_; int w = rem - h*W_;
  float patch[C_*9];
  #pragma unroll
  for (int ci=0; ci<C_; ++ci){
    const float* ip = img + (size_t)(b*C_+ci)*HW_;
    #pragma unroll
    for (int kh=0; kh<3; ++kh){
      int hh = h + kh - 1;
      #pragma unroll
      for (int kw=0; kw<3; ++kw){
        int ww = w + kw - 1;
        float v = 0.f;
        if (hh >= 0 && hh < H_ && ww >= 0 && ww < W_) v = ip[hh*W_+ww];
        patch[ci*9+kh*3+kw] = v;
      }
    }
  }
  float* o = fV + (size_t)i*HID_;
  #pragma unroll 4
  for (int oc=0; oc<HID_; ++oc){
    float acc = b_s[oc];
    const float* ws = w_s + oc*C_*9;
    #pragma unroll
    for (int t=0; t<C_*9; ++t) acc += patch[t]*ws[t];
    o[oc] = acc;
  }
}

__global__ void k_iota(int* __restrict__ labels){
  int i = blockIdx.x*blockDim.x + threadIdx.x;
  if (i < N_) labels[i] = i;
}

__global__ void k_scatter(const int* __restrict__ labels, const float* __restrict__ fV,
                          float* __restrict__ fsum, float* __restrict__ cnt){
  int i = blockIdx.x*blockDim.x + threadIdx.x;
  if (i >= N_) return;
  int l = labels[i];
  atomicAdd(cnt+l, 1.0f);
  const float* v = fV + (size_t)i*HID_;
  float* s = fsum + (size_t)l*HID_;
  #pragma unroll
  for (int d=0; d<HID_; ++d) atomicAdd(s+d, v[d]);
}

__global__ void k_mean(const float* __restrict__ cnt, float* __restrict__ fsum){
  int i = blockIdx.x*blockDim.x + threadIdx.x;
  if (i >= N_) return;
  float c = cnt[i];
  if (c > 0.f){
    float* s = fsum + (size_t)i*HID_;
    #pragma unroll
    for (int d=0; d<HID_; ++d) s[d] = s[d] / c;
  }
}

__global__ void k_sim(const int* __restrict__ labels, const float* __restrict__ f,
                      float* __restrict__ sim, unsigned* __restrict__ maxk){
  int u = blockIdx.x*blockDim.x + threadIdx.x;
  if (u >= U_) return;
  int a, b2; edge_uv(u, a, b2);
  int ra = labels[a], rb = labels[b2];
  if (ra == rb){ sim[u] = -1.0f; return; }
  const float* fa = f + (size_t)ra*HID_;
  const float* fb = f + (size_t)rb*HID_;
  float d2 = 0.f;
  #pragma unroll
  for (int d=0; d<HID_; ++d){ float t = fa[d]-fb[d]; d2 += t*t; }
  float s = expf(-d2);
  sim[u] = s;
  atomicMax(maxk+ra, fkey(s));
  atomicMax(maxk+rb, fkey(s));
}

__global__ void k_best(const int* __restrict__ labels, const float* __restrict__ sim,
                       const unsigned* __restrict__ maxk, int* __restrict__ best){
  int u = blockIdx.x*blockDim.x + threadIdx.x;
  if (u >= U_) return;
  int a, b2; edge_uv(u, a, b2);
  int ra = labels[a], rb = labels[b2];
  if (ra == rb) return;
  unsigned sk = fkey(sim[u]);
  if (sk >= maxk[ra]) atomicMax(best+ra, rb);
  if (sk >= maxk[rb]) atomicMax(best+rb, ra);
}

__global__ void k_parent(const unsigned* __restrict__ maxk, const int* __restrict__ best,
                         int* __restrict__ par){
  int i = blockIdx.x*blockDim.x + threadIdx.x;
  if (i >= N_) return;
  int b = best[i];
  par[i] = (maxk[i] > K01_ && b >= 0) ? b : i;
}

__global__ void k_break(const int* __restrict__ par, int* __restrict__ par2){
  int i = blockIdx.x*blockDim.x + threadIdx.x;
  if (i >= N_) return;
  int p = par[i];
  int pp = par[p];
  par2[i] = (pp == i && i < p) ? i : p;
}

__global__ void k_root(const int* __restrict__ par2, int* __restrict__ root){
  int i = blockIdx.x*blockDim.x + threadIdx.x;
  if (i >= N_) return;
  int p = par2[i];
  for (int it = 0; it < (1<<20); ++it){
    int g = par2[p];
    if (g == p) break;
    p = g;
  }
  root[i] = p;
}

__global__ void k_relabel(const int* __restrict__ root, int* __restrict__ labels){
  int i = blockIdx.x*blockDim.x + threadIdx.x;
  if (i >= N_) return;
  labels[i] = root[labels[i]];
}

__global__ void k_scatter2(const int* __restrict__ labels, const float* __restrict__ fV,
      const float* __restrict__ img, float* __restrict__ fsum, float* __restrict__ psum,
      float* __restrict__ cnt){
  int i = blockIdx.x*blockDim.x + threadIdx.x;
  if (i >= N_) return;
  int l = labels[i];
  atomicAdd(cnt+l, 1.0f);
  const float* v = fV + (size_t)i*HID_;
  float* s = fsum + (size_t)l*HID_;
  #pragma unroll
  for (int d=0; d<HID_; ++d) atomicAdd(s+d, v[d]);
  int b = i / HW_; int rem = i - b*HW_;
  const float* ip = img + (size_t)b*C_*HW_ + rem;
  float* ps = psum + (size_t)l*C_;
  #pragma unroll
  for (int c=0; c<C_; ++c) atomicAdd(ps+c, ip[(size_t)c*HW_]);
}

__global__ void k_regionfeat(const float* __restrict__ cnt, const float* __restrict__ fsum,
      const float* __restrict__ psum, const float* __restrict__ lw, const float* __restrict__ lb,
      float* __restrict__ rf3){
  int i = blockIdx.x*blockDim.x + threadIdx.x;
  if (i >= N_) return;
  float c = cnt[i];
  if (c <= 0.f) return;
  float fm[HID_];
  const float* s = fsum + (size_t)i*HID_;
  #pragma unroll
  for (int d=0; d<HID_; ++d) fm[d] = s[d] / c;
  #pragma unroll
  for (int cc=0; cc<C_; ++cc){
    float acc = 0.f;
    const float* w = lw + cc*HID_;
    #pragma unroll
    for (int d=0; d<HID_; ++d) acc += fm[d]*w[d];
    rf3[(size_t)i*C_+cc] = (acc + lb[cc]) - psum[(size_t)i*C_+cc]/c;
  }
}

__global__ void k_out(const int* __restrict__ labels, const float* __restrict__ img,
      const float* __restrict__ rf3, float* __restrict__ out, float* __restrict__ outlab){
  int i = blockIdx.x*blockDim.x + threadIdx.x;
  if (i >= N_) return;
  int l = labels[i];
  int b = i / HW_; int rem = i - b*HW_;
  const float* ip = img + (size_t)b*C_*HW_ + rem;
  #pragma unroll
  for (int c=0; c<C_; ++c)
    out[(size_t)i*C_+c] = ip[(size_t)c*HW_] + rf3[(size_t)l*C_+c];
  outlab[i] = (float)l;
}

extern "C" void kernel_launch(void* const* d_in, const int* in_sizes, int n_in,
                              void* d_out, int out_size, void* d_ws, size_t ws_size,
                              hipStream_t stream) {
  const float* img = (const float*)d_in[0];
  const float* cw  = (const float*)d_in[1];
  const float* cb  = (const float*)d_in[2];
  const float* lw  = (const float*)d_in[3];
  const float* lb  = (const float*)d_in[4];

  char* ws = (char*)d_ws;
  size_t off = 0;
  auto alloc = [&](size_t bytes) -> void* {
    void* p = ws + off; off += (bytes + 255) & ~(size_t)255; return p;
  };
  float*    fV     = (float*)   alloc((size_t)N_*HID_*4);
  float*    f      = (float*)   alloc((size_t)N_*HID_*4);
  float*    cnt    = (float*)   alloc((size_t)N_*4);
  unsigned* maxk   = (unsigned*)alloc((size_t)N_*4);
  int*      best   = (int*)     alloc((size_t)N_*4);
  int*      par    = (int*)     alloc((size_t)N_*4);
  int*      par2   = (int*)     alloc((size_t)N_*4);
  int*      root   = (int*)     alloc((size_t)N_*4);
  int*      labels = (int*)     alloc((size_t)N_*4);
  float*    sim    = (float*)   alloc((size_t)U_*4);
  float*    psum   = (float*)   alloc((size_t)N_*C_*4);
  float*    rf3    = (float*)   alloc((size_t)N_*C_*4);

  dim3 blk(256);
  int gN = (N_ + 255) / 256;
  int gU = (U_ + 255) / 256;

  k_conv<<<gN, blk, 0, stream>>>(img, cw, cb, fV);
  k_iota<<<gN, blk, 0, stream>>>(labels);

  for (int it = 0; it < 8; ++it) {
    const float* fcur;
    if (it == 0) {
      fcur = fV;   // labels == iota -> segment mean of singletons == fV exactly
    } else {
      hipMemsetAsync(f,   0, (size_t)N_*HID_*4, stream);
      hipMemsetAsync(cnt, 0, (size_t)N_*4,      stream);
      k_scatter<<<gN, blk, 0, stream>>>(labels, fV, f, cnt);
      k_mean<<<gN, blk, 0, stream>>>(cnt, f);
      fcur = f;
    }
    hipMemsetAsync(maxk, 0,    (size_t)N_*4, stream);
    hipMemsetAsync(best, 0xFF, (size_t)N_*4, stream);
    k_sim<<<gU, blk, 0, stream>>>(labels, fcur, sim, maxk);
    k_best<<<gU, blk, 0, stream>>>(labels, sim, maxk, best);
    k_parent<<<gN, blk, 0, stream>>>(maxk, best, par);
    k_break<<<gN, blk, 0, stream>>>(par, par2);
    k_root<<<gN, blk, 0, stream>>>(par2, root);
    k_relabel<<<gN, blk, 0, stream>>>(root, labels);
  }

  hipMemsetAsync(f,    0, (size_t)N_*HID_*4, stream);
  hipMemsetAsync(cnt,  0, (size_t)N_*4,      stream);
  hipMemsetAsync(psum, 0, (size_t)N_*C_*4,   stream);
  k_scatter2<<<gN, blk, 0, stream>>>(labels, fV, img, f, psum, cnt);
  k_regionfeat<<<gN, blk, 0, stream>>>(cnt, f, psum, lw, lb, rf3);

  float* out = (float*)d_out;
  k_out<<<gN, blk, 0, stream>>>(labels, img, rf3, out, out + (size_t)N_*C_);
}

// Round 2
// 636.141 us; speedup vs baseline: 11.6464x; 11.6464x over previous
//
#include <hip/hip_runtime.h>

#define B_ 8
#define C_ 3
#define H_ 256
#define W_ 256
#define HID_ 32
#define HW_ (H_*W_)            // 65536
#define N_ (B_*H_*W_)          // 524288
#define EH_ (B_*H_*(W_-1))     // 522240 horizontal undirected edges
#define EV_ (B_*(H_-1)*W_)     // 522240 vertical undirected edges
#define U_ (EH_+EV_)           // 1044480
#define K01_ 0xBDCCCCCDu       // fkey(0.1f)

__device__ __forceinline__ unsigned fkey(float f){
  unsigned u = __float_as_uint(f);
  return (u & 0x80000000u) ? ~u : (u | 0x80000000u);
}

__device__ __forceinline__ void edge_uv(int u, int& a, int& b){
  if (u < EH_){
    int w = u % (W_-1); int t = u / (W_-1); int h = t % H_; int bb = t / H_;
    a = (bb*H_+h)*W_+w; b = a+1;
  } else {
    int v = u - EH_;
    int w = v % W_; int t = v / W_; int h = t % (H_-1); int bb = t / (H_-1);
    a = (bb*H_+h)*W_+w; b = a+W_;
  }
}

// conv backbone -> per-pixel hidden features, written directly as the initial
// region sums (every pixel its own region, cnt=1)
__global__ __launch_bounds__(256) void k_conv(const float* __restrict__ img,
    const float* __restrict__ cw, const float* __restrict__ cb,
    float* __restrict__ fsum){
  __shared__ float w_s[HID_*C_*9];
  __shared__ float b_s[HID_];
  for (int t = threadIdx.x; t < HID_*C_*9; t += blockDim.x) w_s[t] = cw[t];
  if (threadIdx.x < HID_) b_s[threadIdx.x] = cb[threadIdx.x];
  __syncthreads();
  int i = blockIdx.x*blockDim.x + threadIdx.x;
  if (i >= N_) return;
  int b = i / HW_; int rem = i - b*HW_; int h = rem / W_; int w = rem - h*W_;
  float patch[C_*9];
  #pragma unroll
  for (int ci=0; ci<C_; ++ci){
    const float* ip = img + (size_t)(b*C_+ci)*HW_;
    #pragma unroll
    for (int kh=0; kh<3; ++kh){
      int hh = h + kh - 1;
      #pragma unroll
      for (int kw=0; kw<3; ++kw){
        int ww = w + kw - 1;
        float v = 0.f;
        if (hh >= 0 && hh < H_ && ww >= 0 && ww < W_) v = ip[hh*W_+ww];
        patch[ci*9+kh*3+kw] = v;
      }
    }
  }
  float* o = fsum + (size_t)i*HID_;
  #pragma unroll 4
  for (int oc=0; oc<HID_; ++oc){
    float acc = b_s[oc];
    const float* ws = w_s + oc*C_*9;
    #pragma unroll
    for (int t=0; t<C_*9; ++t) acc += patch[t]*ws[t];
    o[oc] = acc;
  }
}

__global__ void k_init(const float* __restrict__ img, int* __restrict__ labels,
                       float* __restrict__ cnt, float* __restrict__ psum){
  int i = blockIdx.x*blockDim.x + threadIdx.x;
  if (i >= N_) return;
  labels[i] = i;
  cnt[i] = 1.0f;
  int b = i / HW_; int rem = i - b*HW_;
  const float* ip = img + (size_t)b*C_*HW_ + rem;
  #pragma unroll
  for (int c=0; c<C_; ++c) psum[(size_t)i*C_+c] = ip[(size_t)c*HW_];
}

// per-edge similarity between region means (sum/cnt on the fly) + scatter-max
__global__ void k_sim(const int* __restrict__ labels, const float* __restrict__ fsum,
                      const float* __restrict__ cnt,
                      float* __restrict__ sim, unsigned* __restrict__ maxk){
  int u = blockIdx.x*blockDim.x + threadIdx.x;
  if (u >= U_) return;
  int a, b2; edge_uv(u, a, b2);
  int ra = labels[a], rb = labels[b2];
  if (ra == rb) return;          // intra-region entries never read downstream
  float rca = 1.0f / cnt[ra];
  float rcb = 1.0f / cnt[rb];
  const float* fa = fsum + (size_t)ra*HID_;
  const float* fb = fsum + (size_t)rb*HID_;
  float d2 = 0.f;
  #pragma unroll
  for (int d=0; d<HID_; ++d){ float t = fa[d]*rca - fb[d]*rcb; d2 += t*t; }
  float s = expf(-d2);
  sim[u] = s;
  unsigned sk = fkey(s);
  atomicMax(maxk+ra, sk);
  atomicMax(maxk+rb, sk);
}

__global__ void k_best(const int* __restrict__ labels, const float* __restrict__ sim,
                       const unsigned* __restrict__ maxk, int* __restrict__ best){
  int u = blockIdx.x*blockDim.x + threadIdx.x;
  if (u >= U_) return;
  int a, b2; edge_uv(u, a, b2);
  int ra = labels[a], rb = labels[b2];
  if (ra == rb) return;
  unsigned sk = fkey(sim[u]);
  if (sk >= maxk[ra]) atomicMax(best+ra, rb);
  if (sk >= maxk[rb]) atomicMax(best+rb, ra);
}

__global__ void k_parent(const unsigned* __restrict__ maxk, const int* __restrict__ best,
                         int* __restrict__ par){
  int i = blockIdx.x*blockDim.x + threadIdx.x;
  if (i >= N_) return;
  int b = best[i];
  par[i] = (maxk[i] > K01_ && b >= 0) ? b : i;
}

__global__ void k_break(const int* __restrict__ par, int* __restrict__ par2){
  int i = blockIdx.x*blockDim.x + threadIdx.x;
  if (i >= N_) return;
  int p = par[i];
  int pp = par[p];
  par2[i] = (pp == i && i < p) ? i : p;
}

__global__ void k_root(const int* __restrict__ par2, int* __restrict__ root){
  int i = blockIdx.x*blockDim.x + threadIdx.x;
  if (i >= N_) return;
  int p = par2[i];
  for (int it = 0; it < (1<<20); ++it){
    int g = par2[p];
    if (g == p) break;
    p = g;
  }
  root[i] = p;
}

// fold sums of dying roots into their new root. old roots = {i: labels[i]==i}
// (labels not yet relabeled). Readers (root[i]!=i) and writers (root slots)
// are disjoint index sets -> race-free.
__global__ void k_merge(const int* __restrict__ labels, const int* __restrict__ root,
                        float* __restrict__ fsum, float* __restrict__ psum,
                        float* __restrict__ cnt){
  int i = blockIdx.x*blockDim.x + threadIdx.x;
  if (i >= N_) return;
  if (labels[i] != i) return;    // not a live region
  int r = root[i];
  if (r == i) return;            // survives as root
  atomicAdd(cnt+r, cnt[i]);
  const float* s = fsum + (size_t)i*HID_;
  float* dsum = fsum + (size_t)r*HID_;
  #pragma unroll
  for (int d=0; d<HID_; ++d) atomicAdd(dsum+d, s[d]);
  const float* p = psum + (size_t)i*C_;
  float* dp = psum + (size_t)r*C_;
  #pragma unroll
  for (int c=0; c<C_; ++c) atomicAdd(dp+c, p[c]);
}

__global__ void k_relabel(const int* __restrict__ root, int* __restrict__ labels){
  int i = blockIdx.x*blockDim.x + threadIdx.x;
  if (i >= N_) return;
  labels[i] = root[labels[i]];
}

__global__ void k_regionfeat(const int* __restrict__ labels, const float* __restrict__ cnt,
      const float* __restrict__ fsum, const float* __restrict__ psum,
      const float* __restrict__ lw, const float* __restrict__ lb,
      float* __restrict__ rf3){
  int i = blockIdx.x*blockDim.x + threadIdx.x;
  if (i >= N_) return;
  if (labels[i] != i) return;    // only live regions
  float rc = 1.0f / cnt[i];
  float fm[HID_];
  const float* s = fsum + (size_t)i*HID_;
  #pragma unroll
  for (int d=0; d<HID_; ++d) fm[d] = s[d] * rc;
  #pragma unroll
  for (int cc=0; cc<C_; ++cc){
    float acc = 0.f;
    const float* w = lw + cc*HID_;
    #pragma unroll
    for (int d=0; d<HID_; ++d) acc += fm[d]*w[d];
    rf3[(size_t)i*C_+cc] = (acc + lb[cc]) - psum[(size_t)i*C_+cc]*rc;
  }
}

__global__ void k_out(const int* __restrict__ labels, const float* __restrict__ img,
      const float* __restrict__ rf3, float* __restrict__ out, float* __restrict__ outlab){
  int i = blockIdx.x*blockDim.x + threadIdx.x;
  if (i >= N_) return;
  int l = labels[i];
  int b = i / HW_; int rem = i - b*HW_;
  const float* ip = img + (size_t)b*C_*HW_ + rem;
  #pragma unroll
  for (int c=0; c<C_; ++c)
    out[(size_t)i*C_+c] = ip[(size_t)c*HW_] + rf3[(size_t)l*C_+c];
  outlab[i] = (float)l;
}

extern "C" void kernel_launch(void* const* d_in, const int* in_sizes, int n_in,
                              void* d_out, int out_size, void* d_ws, size_t ws_size,
                              hipStream_t stream) {
  const float* img = (const float*)d_in[0];
  const float* cw  = (const float*)d_in[1];
  const float* cb  = (const float*)d_in[2];
  const float* lw  = (const float*)d_in[3];
  const float* lb  = (const float*)d_in[4];

  char* ws = (char*)d_ws;
  size_t off = 0;
  auto alloc = [&](size_t bytes) -> void* {
    void* p = ws + off; off += (bytes + 255) & ~(size_t)255; return p;
  };
  float*    fsum   = (float*)   alloc((size_t)N_*HID_*4);
  float*    psum   = (float*)   alloc((size_t)N_*C_*4);
  float*    cnt    = (float*)   alloc((size_t)N_*4);
  unsigned* maxk   = (unsigned*)alloc((size_t)N_*4);
  int*      best   = (int*)     alloc((size_t)N_*4);
  int*      par    = (int*)     alloc((size_t)N_*4);
  int*      par2   = (int*)     alloc((size_t)N_*4);
  int*      root   = (int*)     alloc((size_t)N_*4);
  int*      labels = (int*)     alloc((size_t)N_*4);
  float*    sim    = (float*)   alloc((size_t)U_*4);
  float*    rf3    = (float*)   alloc((size_t)N_*C_*4);

  dim3 blk(256);
  int gN = (N_ + 255) / 256;
  int gU = (U_ + 255) / 256;

  k_conv<<<gN, blk, 0, stream>>>(img, cw, cb, fsum);
  k_init<<<gN, blk, 0, stream>>>(img, labels, cnt, psum);

  for (int it = 0; it < 8; ++it) {
    hipMemsetAsync(maxk, 0,    (size_t)N_*4, stream);
    hipMemsetAsync(best, 0xFF, (size_t)N_*4, stream);
    k_sim<<<gU, blk, 0, stream>>>(labels, fsum, cnt, sim, maxk);
    k_best<<<gU, blk, 0, stream>>>(labels, sim, maxk, best);
    k_parent<<<gN, blk, 0, stream>>>(maxk, best, par);
    k_break<<<gN, blk, 0, stream>>>(par, par2);
    k_root<<<gN, blk, 0, stream>>>(par2, root);
    k_merge<<<gN, blk, 0, stream>>>(labels, root, fsum, psum, cnt);
    k_relabel<<<gN, blk, 0, stream>>>(root, labels);
  }

  k_regionfeat<<<gN, blk, 0, stream>>>(labels, cnt, fsum, psum, lw, lb, rf3);

  float* out = (float*)d_out;
  k_out<<<gN, blk, 0, stream>>>(labels, img, rf3, out, out + (size_t)N_*C_);
}

// Round 3
// 362.955 us; speedup vs baseline: 20.4123x; 1.7527x over previous
//
#include <hip/hip_runtime.h>

#define B_ 8
#define C_ 3
#define H_ 256
#define W_ 256
#define HID_ 32
#define HW_ (H_*W_)            // 65536
#define N_ (B_*H_*W_)          // 524288
#define K01_ 0xBDCCCCCDu       // fkey(0.1f)

__device__ __forceinline__ unsigned fkey(float f){
  unsigned u = __float_as_uint(f);
  return (u & 0x80000000u) ? ~u : (u | 0x80000000u);
}

// conv backbone -> per-pixel hidden features written as initial region sums
// (every pixel its own region), plus labels=iota, cnt=1, psum=pixel values.
__global__ __launch_bounds__(256) void k_conv_init(const float* __restrict__ img,
    const float* __restrict__ cw, const float* __restrict__ cb,
    float* __restrict__ fsum, int* __restrict__ labels,
    float* __restrict__ cnt, float* __restrict__ psum){
  __shared__ float w_s[HID_*C_*9];
  __shared__ float b_s[HID_];
  for (int t = threadIdx.x; t < HID_*C_*9; t += blockDim.x) w_s[t] = cw[t];
  if (threadIdx.x < HID_) b_s[threadIdx.x] = cb[threadIdx.x];
  __syncthreads();
  int i = blockIdx.x*blockDim.x + threadIdx.x;
  if (i >= N_) return;
  int b = i / HW_; int rem = i - b*HW_; int h = rem / W_; int w = rem - h*W_;
  float patch[C_*9];
  #pragma unroll
  for (int ci=0; ci<C_; ++ci){
    const float* ip = img + (size_t)(b*C_+ci)*HW_;
    #pragma unroll
    for (int kh=0; kh<3; ++kh){
      int hh = h + kh - 1;
      #pragma unroll
      for (int kw=0; kw<3; ++kw){
        int ww = w + kw - 1;
        float v = 0.f;
        if (hh >= 0 && hh < H_ && ww >= 0 && ww < W_) v = ip[hh*W_+ww];
        patch[ci*9+kh*3+kw] = v;
      }
    }
  }
  float* o = fsum + (size_t)i*HID_;
  #pragma unroll 4
  for (int oc=0; oc<HID_; ++oc){
    float acc = b_s[oc];
    const float* ws = w_s + oc*C_*9;
    #pragma unroll
    for (int t=0; t<C_*9; ++t) acc += patch[t]*ws[t];
    o[oc] = acc;
  }
  labels[i] = i;
  cnt[i] = 1.0f;
  #pragma unroll
  for (int c=0; c<C_; ++c) psum[(size_t)i*C_+c] = patch[c*9+4];  // center pixel
}

// one thread per pixel: handles right edge (i,i+1) and down edge (i,i+W).
// packed scatter-argmax: (fkey(sim)<<32)|neighbor_region. High-word equality
// == float equality, so low-word max == reference's "max rb among argmax".
__global__ void k_simbest(const int* __restrict__ labels,
                          const float* __restrict__ fsum, const float* __restrict__ cnt,
                          unsigned long long* __restrict__ maxk64){
  int i = blockIdx.x*blockDim.x + threadIdx.x;
  if (i >= N_) return;
  int rem = i & (HW_-1); int h = rem / W_; int w = rem - h*W_;
  int ri = labels[i];
  int rR = (w < W_-1) ? labels[i+1]  : ri;
  int rD = (h < H_-1) ? labels[i+W_] : ri;
  bool eR = (rR != ri), eD = (rD != ri);
  if (!eR && !eD) return;
  float rci = 1.0f / cnt[ri];
  const float* fi = fsum + (size_t)ri*HID_;
  float mi[HID_];
  #pragma unroll
  for (int d=0; d<HID_; ++d) mi[d] = fi[d]*rci;
  if (eR){
    float rcj = 1.0f / cnt[rR];
    const float* fj = fsum + (size_t)rR*HID_;
    float d2 = 0.f;
    #pragma unroll
    for (int d=0; d<HID_; ++d){ float t = mi[d] - fj[d]*rcj; d2 += t*t; }
    unsigned long long sk = (unsigned long long)fkey(expf(-d2)) << 32;
    atomicMax(maxk64+ri, sk | (unsigned)rR);
    atomicMax(maxk64+rR, sk | (unsigned)ri);
  }
  if (eD){
    float rcj = 1.0f / cnt[rD];
    const float* fj = fsum + (size_t)rD*HID_;
    float d2 = 0.f;
    #pragma unroll
    for (int d=0; d<HID_; ++d){ float t = mi[d] - fj[d]*rcj; d2 += t*t; }
    unsigned long long sk = (unsigned long long)fkey(expf(-d2)) << 32;
    atomicMax(maxk64+ri, sk | (unsigned)rD);
    atomicMax(maxk64+rD, sk | (unsigned)ri);
  }
}

__device__ __forceinline__ int parent_of(const unsigned long long* mk, int i){
  unsigned long long m = mk[i];
  return ((unsigned)(m >> 32) > K01_) ? (int)(m & 0xffffffffu) : i;
}

// parent + 2-cycle break in one pass (parent recomputed inline at i and p)
__global__ void k_parbreak(const unsigned long long* __restrict__ maxk64,
                           int* __restrict__ par2){
  int i = blockIdx.x*blockDim.x + threadIdx.x;
  if (i >= N_) return;
  int p  = parent_of(maxk64, i);
  int pp = parent_of(maxk64, p);
  par2[i] = (pp == i && i < p) ? i : p;
}

// chase to root from labels[i]; fold dying-root sums; relabel. Dying roots
// (labels[i]==i, root!=i) are read-only slots; writes target surviving roots
// only -> disjoint, race-free. Threads never read other threads' labels.
__global__ void k_update(const int* __restrict__ par2, int* __restrict__ labels,
                         float* __restrict__ fsum, float* __restrict__ psum,
                         float* __restrict__ cnt){
  int i = blockIdx.x*blockDim.x + threadIdx.x;
  if (i >= N_) return;
  int l = labels[i];
  int p = par2[l];
  for (int it = 0; it < 4096; ++it){
    int g = par2[p];
    if (g == p) break;
    p = g;
  }
  if (l == i && p != i){
    atomicAdd(cnt+p, cnt[i]);
    const float* s = fsum + (size_t)i*HID_;
    float* ds = fsum + (size_t)p*HID_;
    #pragma unroll
    for (int d=0; d<HID_; ++d) atomicAdd(ds+d, s[d]);
    const float* ps = psum + (size_t)i*C_;
    float* dp = psum + (size_t)p*C_;
    #pragma unroll
    for (int c=0; c<C_; ++c) atomicAdd(dp+c, ps[c]);
  }
  labels[i] = p;
}

__global__ void k_regionfeat(const int* __restrict__ labels, const float* __restrict__ cnt,
      const float* __restrict__ fsum, const float* __restrict__ psum,
      const float* __restrict__ lw, const float* __restrict__ lb,
      float* __restrict__ rf3){
  int i = blockIdx.x*blockDim.x + threadIdx.x;
  if (i >= N_) return;
  if (labels[i] != i) return;    // only live regions
  float rc = 1.0f / cnt[i];
  float fm[HID_];
  const float* s = fsum + (size_t)i*HID_;
  #pragma unroll
  for (int d=0; d<HID_; ++d) fm[d] = s[d] * rc;
  #pragma unroll
  for (int cc=0; cc<C_; ++cc){
    float acc = 0.f;
    const float* w = lw + cc*HID_;
    #pragma unroll
    for (int d=0; d<HID_; ++d) acc += fm[d]*w[d];
    rf3[(size_t)i*C_+cc] = (acc + lb[cc]) - psum[(size_t)i*C_+cc]*rc;
  }
}

__global__ void k_out(const int* __restrict__ labels, const float* __restrict__ img,
      const float* __restrict__ rf3, float* __restrict__ out, float* __restrict__ outlab){
  int i = blockIdx.x*blockDim.x + threadIdx.x;
  if (i >= N_) return;
  int l = labels[i];
  int b = i / HW_; int rem = i - b*HW_;
  const float* ip = img + (size_t)b*C_*HW_ + rem;
  #pragma unroll
  for (int c=0; c<C_; ++c)
    out[(size_t)i*C_+c] = ip[(size_t)c*HW_] + rf3[(size_t)l*C_+c];
  outlab[i] = (float)l;
}

extern "C" void kernel_launch(void* const* d_in, const int* in_sizes, int n_in,
                              void* d_out, int out_size, void* d_ws, size_t ws_size,
                              hipStream_t stream) {
  const float* img = (const float*)d_in[0];
  const float* cw  = (const float*)d_in[1];
  const float* cb  = (const float*)d_in[2];
  const float* lw  = (const float*)d_in[3];
  const float* lb  = (const float*)d_in[4];

  char* ws = (char*)d_ws;
  size_t off = 0;
  auto alloc = [&](size_t bytes) -> void* {
    void* p = ws + off; off += (bytes + 255) & ~(size_t)255; return p;
  };
  float*              fsum   = (float*)              alloc((size_t)N_*HID_*4);
  float*              psum   = (float*)              alloc((size_t)N_*C_*4);
  float*              cnt    = (float*)              alloc((size_t)N_*4);
  unsigned long long* maxk64 = (unsigned long long*) alloc((size_t)N_*8);
  int*                par2   = (int*)                alloc((size_t)N_*4);
  int*                labels = (int*)                alloc((size_t)N_*4);
  float*              rf3    = (float*)              alloc((size_t)N_*C_*4);

  dim3 blk(256);
  int gN = (N_ + 255) / 256;

  k_conv_init<<<gN, blk, 0, stream>>>(img, cw, cb, fsum, labels, cnt, psum);

  for (int it = 0; it < 8; ++it) {
    hipMemsetAsync(maxk64, 0, (size_t)N_*8, stream);
    k_simbest<<<gN, blk, 0, stream>>>(labels, fsum, cnt, maxk64);
    k_parbreak<<<gN, blk, 0, stream>>>(maxk64, par2);
    k_update<<<gN, blk, 0, stream>>>(par2, labels, fsum, psum, cnt);
  }

  k_regionfeat<<<gN, blk, 0, stream>>>(labels, cnt, fsum, psum, lw, lb, rf3);

  float* out = (float*)d_out;
  k_out<<<gN, blk, 0, stream>>>(labels, img, rf3, out, out + (size_t)N_*C_);
}

// Round 4
// 343.352 us; speedup vs baseline: 21.5777x; 1.0571x over previous
//
#include <hip/hip_runtime.h>

#define B_ 8
#define C_ 3
#define H_ 256
#define W_ 256
#define HID_ 32
#define HW_ (H_*W_)            // 65536
#define N_ (B_*H_*W_)          // 524288
#define K01_ 0xBDCCCCCDu       // fkey(0.1f)

__device__ __forceinline__ unsigned fkey(float f){
  unsigned u = __float_as_uint(f);
  return (u & 0x80000000u) ? ~u : (u | 0x80000000u);
}

// conv backbone -> per-pixel hidden features written (float4) as initial
// region sums; labels=iota, cnt=1, psum=center pixel.
__global__ __launch_bounds__(256) void k_conv_init(const float* __restrict__ img,
    const float* __restrict__ cw, const float* __restrict__ cb,
    float* __restrict__ fsum, int* __restrict__ labels,
    float* __restrict__ cnt, float* __restrict__ psum){
  __shared__ float w_s[HID_*C_*9];
  __shared__ float b_s[HID_];
  for (int t = threadIdx.x; t < HID_*C_*9; t += blockDim.x) w_s[t] = cw[t];
  if (threadIdx.x < HID_) b_s[threadIdx.x] = cb[threadIdx.x];
  __syncthreads();
  int i = blockIdx.x*blockDim.x + threadIdx.x;
  if (i >= N_) return;
  int b = i >> 16; int rem = i & (HW_-1); int h = rem >> 8; int w = rem & (W_-1);
  float patch[C_*9];
  #pragma unroll
  for (int ci=0; ci<C_; ++ci){
    const float* ip = img + (size_t)(b*C_+ci)*HW_;
    #pragma unroll
    for (int kh=0; kh<3; ++kh){
      int hh = h + kh - 1;
      #pragma unroll
      for (int kw=0; kw<3; ++kw){
        int ww = w + kw - 1;
        float v = 0.f;
        if (hh >= 0 && hh < H_ && ww >= 0 && ww < W_) v = ip[hh*W_+ww];
        patch[ci*9+kh*3+kw] = v;
      }
    }
  }
  float acc[HID_];
  #pragma unroll 4
  for (int oc=0; oc<HID_; ++oc){
    float a = b_s[oc];
    const float* ws = w_s + oc*C_*9;
    #pragma unroll
    for (int t=0; t<C_*9; ++t) a += patch[t]*ws[t];
    acc[oc] = a;
  }
  float4* o4 = (float4*)(fsum + (size_t)i*HID_);
  #pragma unroll
  for (int k=0; k<HID_/4; ++k)
    o4[k] = make_float4(acc[4*k], acc[4*k+1], acc[4*k+2], acc[4*k+3]);
  labels[i] = i;
  cnt[i] = 1.0f;
  #pragma unroll
  for (int c=0; c<C_; ++c) psum[(size_t)i*C_+c] = patch[c*9+4];  // center pixel
}

// one thread per pixel: right edge (i,i+1) and down edge (i,i+W).
// packed scatter-argmax: (fkey(sim)<<32)|neighbor_region. High-word equality
// == float equality, so low-word max == reference's "max rb among argmax".
// IT0: labels==iota, cnt==1 -> skip those loads.
template<bool IT0>
__global__ void k_simbest(const int* __restrict__ labels,
                          const float* __restrict__ fsum, const float* __restrict__ cnt,
                          unsigned long long* __restrict__ maxk64){
  int i = blockIdx.x*blockDim.x + threadIdx.x;
  if (i >= N_) return;
  int rem = i & (HW_-1); int h = rem >> 8; int w = rem & (W_-1);
  int ri, rR, rD;
  if (IT0){
    ri = i;
    rR = (w < W_-1) ? i+1  : ri;
    rD = (h < H_-1) ? i+W_ : ri;
  } else {
    ri = labels[i];
    rR = (w < W_-1) ? labels[i+1]  : ri;
    rD = (h < H_-1) ? labels[i+W_] : ri;
  }
  bool eR = (rR != ri), eD = (rD != ri);
  if (!eR && !eD) return;
  float rci = IT0 ? 1.0f : 1.0f / cnt[ri];
  const float4* fi = (const float4*)(fsum + (size_t)ri*HID_);
  float4 mi[HID_/4];
  #pragma unroll
  for (int k=0; k<HID_/4; ++k){
    float4 v = fi[k];
    mi[k] = make_float4(v.x*rci, v.y*rci, v.z*rci, v.w*rci);
  }
  if (eR){
    float rcj = IT0 ? 1.0f : 1.0f / cnt[rR];
    const float4* fj = (const float4*)(fsum + (size_t)rR*HID_);
    float d2 = 0.f;
    #pragma unroll
    for (int k=0; k<HID_/4; ++k){
      float4 v = fj[k];
      float tx = mi[k].x - v.x*rcj; float ty = mi[k].y - v.y*rcj;
      float tz = mi[k].z - v.z*rcj; float tw = mi[k].w - v.w*rcj;
      d2 += tx*tx + ty*ty + tz*tz + tw*tw;
    }
    unsigned long long sk = (unsigned long long)fkey(expf(-d2)) << 32;
    atomicMax(maxk64+ri, sk | (unsigned)rR);
    atomicMax(maxk64+rR, sk | (unsigned)ri);
  }
  if (eD){
    float rcj = IT0 ? 1.0f : 1.0f / cnt[rD];
    const float4* fj = (const float4*)(fsum + (size_t)rD*HID_);
    float d2 = 0.f;
    #pragma unroll
    for (int k=0; k<HID_/4; ++k){
      float4 v = fj[k];
      float tx = mi[k].x - v.x*rcj; float ty = mi[k].y - v.y*rcj;
      float tz = mi[k].z - v.z*rcj; float tw = mi[k].w - v.w*rcj;
      d2 += tx*tx + ty*ty + tz*tz + tw*tw;
    }
    unsigned long long sk = (unsigned long long)fkey(expf(-d2)) << 32;
    atomicMax(maxk64+ri, sk | (unsigned)rD);
    atomicMax(maxk64+rD, sk | (unsigned)ri);
  }
}

// on-the-fly par2(x): p=parent(x); pp=parent(p); (pp==x && x<p) ? x : p
// chase to fixpoint from labels[i]; fold dying-root sums; relabel; clear the
// next iteration's maxk buffer (double-buffered -> no per-iter memset).
// Dying roots are read-only slots; adds target surviving roots only.
__global__ void k_update(const unsigned long long* __restrict__ mk,
                         unsigned long long* __restrict__ mkNext,
                         int* __restrict__ labels,
                         float* __restrict__ fsum, float* __restrict__ psum,
                         float* __restrict__ cnt){
  int i = blockIdx.x*blockDim.x + threadIdx.x;
  if (i >= N_) return;
  mkNext[i] = 0ULL;
  int l = labels[i];
  int x = l;
  for (int it = 0; it < (1<<20); ++it){
    unsigned long long m = mk[x];
    int p = ((unsigned)(m >> 32) > K01_) ? (int)(m & 0xffffffffu) : x;
    if (p == x) break;
    unsigned long long m2 = mk[p];
    int pp = ((unsigned)(m2 >> 32) > K01_) ? (int)(m2 & 0xffffffffu) : p;
    if (pp == x && x < p) break;     // broken 2-cycle: x is the root
    x = p;
  }
  if (l == i && x != i){             // dying root: fold into surviving root
    atomicAdd(cnt+x, cnt[i]);
    const float* s = fsum + (size_t)i*HID_;
    float* ds = fsum + (size_t)x*HID_;
    #pragma unroll
    for (int d=0; d<HID_; ++d) atomicAdd(ds+d, s[d]);
    const float* ps = psum + (size_t)i*C_;
    float* dp = psum + (size_t)x*C_;
    #pragma unroll
    for (int c=0; c<C_; ++c) atomicAdd(dp+c, ps[c]);
  }
  labels[i] = x;
}

// finalize fused: per-pixel recompute of region feature at its root
// (root rows are few and L2-hot), mean injection, labels as float.
__global__ __launch_bounds__(256) void k_out(const int* __restrict__ labels,
      const float* __restrict__ img, const float* __restrict__ cnt,
      const float* __restrict__ fsum, const float* __restrict__ psum,
      const float* __restrict__ lw, const float* __restrict__ lb,
      float* __restrict__ out, float* __restrict__ outlab){
  __shared__ float lw_s[C_*HID_];
  __shared__ float lb_s[C_];
  for (int t = threadIdx.x; t < C_*HID_; t += blockDim.x) lw_s[t] = lw[t];
  if (threadIdx.x < C_) lb_s[threadIdx.x] = lb[threadIdx.x];
  __syncthreads();
  int i = blockIdx.x*blockDim.x + threadIdx.x;
  if (i >= N_) return;
  int l = labels[i];
  float rc = 1.0f / cnt[l];
  const float* s = fsum + (size_t)l*HID_;
  float rf[C_];
  #pragma unroll
  for (int cc=0; cc<C_; ++cc){
    float a = 0.f;
    const float* wv = lw_s + cc*HID_;
    #pragma unroll
    for (int d=0; d<HID_; ++d) a += (s[d]*rc)*wv[d];
    rf[cc] = (a + lb_s[cc]) - psum[(size_t)l*C_+cc]*rc;
  }
  int b = i >> 16; int rem = i & (HW_-1);
  const float* ip = img + (size_t)b*C_*HW_ + rem;
  #pragma unroll
  for (int cc=0; cc<C_; ++cc)
    out[(size_t)i*C_+cc] = ip[(size_t)cc*HW_] + rf[cc];
  outlab[i] = (float)l;
}

extern "C" void kernel_launch(void* const* d_in, const int* in_sizes, int n_in,
                              void* d_out, int out_size, void* d_ws, size_t ws_size,
                              hipStream_t stream) {
  const float* img = (const float*)d_in[0];
  const float* cw  = (const float*)d_in[1];
  const float* cb  = (const float*)d_in[2];
  const float* lw  = (const float*)d_in[3];
  const float* lb  = (const float*)d_in[4];

  char* ws = (char*)d_ws;
  size_t off = 0;
  auto alloc = [&](size_t bytes) -> void* {
    void* p = ws + off; off += (bytes + 255) & ~(size_t)255; return p;
  };
  float*              fsum   = (float*)              alloc((size_t)N_*HID_*4);
  float*              psum   = (float*)              alloc((size_t)N_*C_*4);
  float*              cnt    = (float*)              alloc((size_t)N_*4);
  unsigned long long* mkA    = (unsigned long long*) alloc((size_t)N_*8);
  unsigned long long* mkB    = (unsigned long long*) alloc((size_t)N_*8);
  int*                labels = (int*)                alloc((size_t)N_*4);

  dim3 blk(256);
  int gN = (N_ + 255) / 256;

  hipMemsetAsync(mkA, 0, (size_t)N_*8, stream);   // buf0 initial clear
  k_conv_init<<<gN, blk, 0, stream>>>(img, cw, cb, fsum, labels, cnt, psum);

  for (int it = 0; it < 8; ++it) {
    unsigned long long* mk   = (it & 1) ? mkB : mkA;
    unsigned long long* mkN  = (it & 1) ? mkA : mkB;
    if (it == 0)
      k_simbest<true><<<gN, blk, 0, stream>>>(labels, fsum, cnt, mk);
    else
      k_simbest<false><<<gN, blk, 0, stream>>>(labels, fsum, cnt, mk);
    k_update<<<gN, blk, 0, stream>>>(mk, mkN, labels, fsum, psum, cnt);
  }

  float* out = (float*)d_out;
  k_out<<<gN, blk, 0, stream>>>(labels, img, cnt, fsum, psum, lw, lb,
                                out, out + (size_t)N_*C_);
}